// Round 10
// baseline (315.582 us; speedup 1.0000x reference)
//
#include <hip/hip_runtime.h>
#include <hip/hip_cooperative_groups.h>

namespace cg = cooperative_groups;

#define N_NODES 131072
#define C_IN 32
#define C_OUT 32
#define KTAPS 27
#define BN_EPS 1e-5f
#define TPB 256
#define NBLK 1024   // 4 blocks/CU x 256 CUs, guaranteed by __launch_bounds__(256,4)

typedef __bf16 bf16x8 __attribute__((ext_vector_type(8)));
typedef float  f32x4  __attribute__((ext_vector_type(4)));

// ws layout:
//   xb   : N_NODES rows x 32 bf16 (node-major features)
//   wlay : 27 taps x 2 co-halves x 64 lanes x 8 bf16 (55296 B)
//   sums : 32 sum + 32 sumsq (f32)

static __device__ __forceinline__ unsigned short f2bf(float f) {
    unsigned int u = __float_as_uint(f);
    unsigned int r = (u + 0x7FFFu + ((u >> 16) & 1u)) >> 16;  // RNE
    return (unsigned short)r;
}

__global__ __launch_bounds__(TPB, 4) void k_fused(const float* __restrict__ in,
                                                  const int* __restrict__ neigh,
                                                  const float* __restrict__ w,
                                                  const float* __restrict__ gamma,
                                                  const float* __restrict__ beta,
                                                  float* __restrict__ out,
                                                  unsigned short* __restrict__ xb,
                                                  unsigned short* __restrict__ wlay,
                                                  float* __restrict__ sums) {
    cg::grid_group grid = cg::this_grid();
    __shared__ float bs[C_OUT];
    __shared__ float bq[C_OUT];

    const int tid = threadIdx.x;
    const int gt  = blockIdx.x * TPB + tid;   // 0..262143

    // ---------------- phase 0: prep ----------------
    // transpose [32][N] f32 -> [N][32] bf16; id = c4*N + n keeps reads coalesced over n
#pragma unroll
    for (int it = 0; it < 2; ++it) {
        const int id = gt + it * (NBLK * TPB);
        const int n  = id & (N_NODES - 1);
        const int c4 = id >> 17;  // 0..3
        unsigned short v[8];
#pragma unroll
        for (int j = 0; j < 8; ++j) v[j] = f2bf(in[(size_t)(c4 * 8 + j) * N_NODES + n]);
        uint4 pk;
        pk.x = (unsigned)v[0] | ((unsigned)v[1] << 16);
        pk.y = (unsigned)v[2] | ((unsigned)v[3] << 16);
        pk.z = (unsigned)v[4] | ((unsigned)v[5] << 16);
        pk.w = (unsigned)v[6] | ((unsigned)v[7] << 16);
        *reinterpret_cast<uint4*>(xb + (size_t)n * C_IN + c4 * 8) = pk;
    }
    // weight frag table (A-frag, Out^T = W^T X^T):
    // wlay[((k*2+h)*64+l)*8+j] = w[k*32 + (l>>4)*8+j][h*16 + (l&15)]
    if (blockIdx.x == 1) {
        for (int g = tid; g < KTAPS * 2 * 64; g += TPB) {
            const int k = g >> 7;
            const int rem = g & 127;
            const int h = rem >> 6;
            const int l = rem & 63;
            unsigned short wv[8];
#pragma unroll
            for (int j = 0; j < 8; ++j) {
                const int c  = ((l >> 4) << 3) + j;
                const int co = (h << 4) + (l & 15);
                wv[j] = f2bf(w[(size_t)(k * C_IN + c) * C_OUT + co]);
            }
            uint4 pk;
            pk.x = (unsigned)wv[0] | ((unsigned)wv[1] << 16);
            pk.y = (unsigned)wv[2] | ((unsigned)wv[3] << 16);
            pk.z = (unsigned)wv[4] | ((unsigned)wv[5] << 16);
            pk.w = (unsigned)wv[6] | ((unsigned)wv[7] << 16);
            *reinterpret_cast<uint4*>(wlay + (size_t)g * 8) = pk;
        }
    }
    if (blockIdx.x == 0 && tid < 2 * C_OUT) sums[tid] = 0.f;
    if (tid < C_OUT) { bs[tid] = 0.f; bq[tid] = 0.f; }

    grid.sync();  // xb, wlay, sums=0 visible everywhere (also covers bs/bq)

    // ---------------- phase 1: single-pass conv, 2 interleaved tiles/wave ----------------
    const int wid  = tid >> 6;
    const int lane = tid & 63;
    const int lr   = lane & 15;   // node offset (B/D col)
    const int lg   = lane >> 4;   // channel-slice group
    const int wave = blockIdx.x * 4 + wid;   // 0..4095
    const int nbA  = (2 * wave) * 16;
    const int nbB  = (2 * wave) * 16 + 16;

    const int* nrowA = neigh + (size_t)(nbA + lr) * KTAPS;
    const int* nrowB = neigh + (size_t)(nbB + lr) * KTAPS;

    f32x4 a0 = {0.f, 0.f, 0.f, 0.f}, a1 = {0.f, 0.f, 0.f, 0.f};
    f32x4 b0 = {0.f, 0.f, 0.f, 0.f}, b1 = {0.f, 0.f, 0.f, 0.f};

#pragma unroll
    for (int k = 0; k < KTAPS; ++k) {
        const int idxA = nrowA[k];
        const int idxB = nrowB[k];
        const bf16x8 xfA = *reinterpret_cast<const bf16x8*>(xb + (size_t)idxA * C_IN + lg * 8);
        const bf16x8 xfB = *reinterpret_cast<const bf16x8*>(xb + (size_t)idxB * C_IN + lg * 8);
        const bf16x8 w0 = *reinterpret_cast<const bf16x8*>(wlay + ((size_t)(k * 2 + 0) * 64 + lane) * 8);
        const bf16x8 w1 = *reinterpret_cast<const bf16x8*>(wlay + ((size_t)(k * 2 + 1) * 64 + lane) * 8);
        a0 = __builtin_amdgcn_mfma_f32_16x16x32_bf16(w0, xfA, a0, 0, 0, 0);
        a1 = __builtin_amdgcn_mfma_f32_16x16x32_bf16(w1, xfA, a1, 0, 0, 0);
        b0 = __builtin_amdgcn_mfma_f32_16x16x32_bf16(w0, xfB, b0, 0, 0, 0);
        b1 = __builtin_amdgcn_mfma_f32_16x16x32_bf16(w1, xfB, b1, 0, 0, 0);
    }

    // fused BN stats: combine both tiles, 16-lane reduce -> LDS atomics -> global
    float s0[4], q0[4], s1[4], q1[4];
#pragma unroll
    for (int r = 0; r < 4; ++r) {
        s0[r] = a0[r] + b0[r];  q0[r] = a0[r] * a0[r] + b0[r] * b0[r];
        s1[r] = a1[r] + b1[r];  q1[r] = a1[r] * a1[r] + b1[r] * b1[r];
    }
#pragma unroll
    for (int off = 1; off < 16; off <<= 1) {
#pragma unroll
        for (int r = 0; r < 4; ++r) {
            s0[r] += __shfl_xor(s0[r], off); q0[r] += __shfl_xor(q0[r], off);
            s1[r] += __shfl_xor(s1[r], off); q1[r] += __shfl_xor(q1[r], off);
        }
    }
    if (lr == 0) {
#pragma unroll
        for (int r = 0; r < 4; ++r) {
            atomicAdd(&bs[lg * 4 + r], s0[r]);      atomicAdd(&bq[lg * 4 + r], q0[r]);
            atomicAdd(&bs[16 + lg * 4 + r], s1[r]); atomicAdd(&bq[16 + lg * 4 + r], q1[r]);
        }
    }
    __syncthreads();
    if (tid < C_OUT) {
        atomicAdd(&sums[tid], bs[tid]);
        atomicAdd(&sums[C_OUT + tid], bq[tid]);
    }

    grid.sync();  // all channel sums complete + visible

    // ---------------- phase 2: BN + ReLU from registers, single store ----------------
    const float inv_n = 1.0f / (float)N_NODES;
#pragma unroll
    for (int r = 0; r < 4; ++r) {
        {
            const int row = lg * 4 + r;
            const float mean = sums[row] * inv_n;
            const float var  = sums[C_OUT + row] * inv_n - mean * mean;
            const float sc   = rsqrtf(var + BN_EPS) * gamma[row];
            const float bi   = beta[row] - mean * sc;
            out[(size_t)row * N_NODES + nbA + lr] = fmaxf(fmaf(a0[r], sc, bi), 0.0f);
            out[(size_t)row * N_NODES + nbB + lr] = fmaxf(fmaf(b0[r], sc, bi), 0.0f);
        }
        {
            const int row = 16 + lg * 4 + r;
            const float mean = sums[row] * inv_n;
            const float var  = sums[C_OUT + row] * inv_n - mean * mean;
            const float sc   = rsqrtf(var + BN_EPS) * gamma[row];
            const float bi   = beta[row] - mean * sc;
            out[(size_t)row * N_NODES + nbA + lr] = fmaxf(fmaf(a1[r], sc, bi), 0.0f);
            out[(size_t)row * N_NODES + nbB + lr] = fmaxf(fmaf(b1[r], sc, bi), 0.0f);
        }
    }
}

extern "C" void kernel_launch(void* const* d_in, const int* in_sizes, int n_in,
                              void* d_out, int out_size, void* d_ws, size_t ws_size,
                              hipStream_t stream) {
    const float* data_in = (const float*)d_in[0];
    const int*   neigh   = (const int*)d_in[1];
    const float* weight  = (const float*)d_in[2];
    const float* gamma   = (const float*)d_in[3];
    const float* beta    = (const float*)d_in[4];
    float* out = (float*)d_out;

    unsigned short* xb   = (unsigned short*)d_ws;                 // N*32 bf16
    unsigned short* wlay = xb + (size_t)N_NODES * C_IN;           // 55296 B
    float* sums = (float*)(wlay + (size_t)KTAPS * 2 * 64 * 8);    // 64 f32

    void* args[] = {(void*)&data_in, (void*)&neigh, (void*)&weight, (void*)&gamma,
                    (void*)&beta, (void*)&out, (void*)&xb, (void*)&wlay, (void*)&sums};
    hipLaunchCooperativeKernel((const void*)k_fused, dim3(NBLK), dim3(TPB), args, 0, stream);
}

// Round 11
// 90.341 us; speedup vs baseline: 3.4933x; 3.4933x over previous
//
#include <hip/hip_runtime.h>

#define N_NODES 131072
#define C_IN 32
#define C_OUT 32
#define KTAPS 27
#define BN_EPS 1e-5f
#define BATCH 9

typedef __bf16 bf16x8 __attribute__((ext_vector_type(8)));
typedef float  f32x4  __attribute__((ext_vector_type(4)));

// ws layout:
//   xb   : N_NODES rows x 32 bf16 (node-major features)
//   wlay : 27 taps x 2 co-halves x 64 lanes x 8 bf16 (55296 B)
//   sums : 32 sum + 32 sumsq (f32)

static __device__ __forceinline__ unsigned short f2bf(float f) {
    unsigned int u = __float_as_uint(f);
    unsigned int r = (u + 0x7FFFu + ((u >> 16) & 1u)) >> 16;  // RNE
    return (unsigned short)r;
}

// ---- prep: blocks 0..511 transpose x; block 512 builds wlay + zeroes sums ----
__global__ __launch_bounds__(256) void k_prep(const float* __restrict__ in,
                                              const float* __restrict__ w,
                                              unsigned short* __restrict__ xb,
                                              unsigned short* __restrict__ wlay,
                                              float* __restrict__ sums) {
    if (blockIdx.x < N_NODES / 256) {
        const int n = blockIdx.x * 256 + threadIdx.x;
        unsigned short v[C_IN];
#pragma unroll
        for (int c = 0; c < C_IN; ++c) v[c] = f2bf(in[(size_t)c * N_NODES + n]);
        uint4* dst = reinterpret_cast<uint4*>(xb + (size_t)n * C_IN);
#pragma unroll
        for (int q = 0; q < 4; ++q) {
            uint4 pk;
            pk.x = (unsigned)v[q * 8 + 0] | ((unsigned)v[q * 8 + 1] << 16);
            pk.y = (unsigned)v[q * 8 + 2] | ((unsigned)v[q * 8 + 3] << 16);
            pk.z = (unsigned)v[q * 8 + 4] | ((unsigned)v[q * 8 + 5] << 16);
            pk.w = (unsigned)v[q * 8 + 6] | ((unsigned)v[q * 8 + 7] << 16);
            dst[q] = pk;
        }
    } else {
        if (threadIdx.x < 2 * C_OUT) sums[threadIdx.x] = 0.f;
        // A-frag (Out^T = W^T X^T, 16x16x32):
        // wlay[((k*2+h)*64+l)*8+j] = w[k*32 + (l>>4)*8+j][h*16 + (l&15)]
        for (int g = threadIdx.x; g < KTAPS * 2 * 64; g += 256) {
            const int k = g >> 7;
            const int rem = g & 127;
            const int h = rem >> 6;
            const int l = rem & 63;
            unsigned short wv[8];
#pragma unroll
            for (int j = 0; j < 8; ++j) {
                const int c  = ((l >> 4) << 3) + j;
                const int co = (h << 4) + (l & 15);
                wv[j] = f2bf(w[(size_t)(k * C_IN + c) * C_OUT + co]);
            }
            uint4 pk;
            pk.x = (unsigned)wv[0] | ((unsigned)wv[1] << 16);
            pk.y = (unsigned)wv[2] | ((unsigned)wv[3] << 16);
            pk.z = (unsigned)wv[4] | ((unsigned)wv[5] << 16);
            pk.w = (unsigned)wv[6] | ((unsigned)wv[7] << 16);
            *reinterpret_cast<uint4*>(wlay + (size_t)g * 8) = pk;
        }
    }
}

// ---- conv: single pass, 16 nodes/wave, 9-deep gather batches (Little's-law fix),
//      fused BN stats. 2048 blocks x 256 thr. ----
__global__ __launch_bounds__(256, 4) void k_conv_mfma(const unsigned short* __restrict__ xb,
                                                      const int* __restrict__ neigh,
                                                      const unsigned short* __restrict__ wlay,
                                                      float* __restrict__ out,
                                                      float* __restrict__ sums) {
    __shared__ float bs[C_OUT];
    __shared__ float bq[C_OUT];
    if (threadIdx.x < C_OUT) { bs[threadIdx.x] = 0.f; bq[threadIdx.x] = 0.f; }
    __syncthreads();

    const int wid  = threadIdx.x >> 6;
    const int lane = threadIdx.x & 63;
    const int lr   = lane & 15;   // node offset (B/D col)
    const int lg   = lane >> 4;   // channel-slice group
    const int nb   = blockIdx.x * 64 + wid * 16;

    // all 27 neighbor indices up front
    const int* nrow = neigh + (size_t)(nb + lr) * KTAPS;
    int nidx[KTAPS];
#pragma unroll
    for (int k = 0; k < KTAPS; ++k) nidx[k] = nrow[k];

    f32x4 acc0 = {0.f, 0.f, 0.f, 0.f};
    f32x4 acc1 = {0.f, 0.f, 0.f, 0.f};

#pragma unroll
    for (int b = 0; b < KTAPS / BATCH; ++b) {
        // 1) issue 9 independent gathers — all must stay live until the MFMA
        //    block below, so the compiler cannot sink them (9 outstanding).
        bf16x8 xf[BATCH];
#pragma unroll
        for (int j = 0; j < BATCH; ++j)
            xf[j] = *reinterpret_cast<const bf16x8*>(
                xb + (size_t)nidx[b * BATCH + j] * C_IN + lg * 8);
        // 2) consume: weight loads (independent, L1/L2-hit) + 18 MFMAs
#pragma unroll
        for (int j = 0; j < BATCH; ++j) {
            const int k = b * BATCH + j;
            const bf16x8 w0 = *reinterpret_cast<const bf16x8*>(wlay + ((size_t)(k * 2 + 0) * 64 + lane) * 8);
            const bf16x8 w1 = *reinterpret_cast<const bf16x8*>(wlay + ((size_t)(k * 2 + 1) * 64 + lane) * 8);
            acc0 = __builtin_amdgcn_mfma_f32_16x16x32_bf16(w0, xf[j], acc0, 0, 0, 0);
            acc1 = __builtin_amdgcn_mfma_f32_16x16x32_bf16(w1, xf[j], acc1, 0, 0, 0);
        }
    }

    // D layout: col = lr -> node, row = lg*4 + r -> c_out
#pragma unroll
    for (int r = 0; r < 4; ++r) {
        out[(size_t)(lg * 4 + r) * N_NODES + nb + lr]      = acc0[r];
        out[(size_t)(16 + lg * 4 + r) * N_NODES + nb + lr] = acc1[r];
    }

    // fused BN stats: 16-lane in-register reduce -> LDS atomics -> global atomics
    float s0[4], q0[4], s1[4], q1[4];
#pragma unroll
    for (int r = 0; r < 4; ++r) {
        s0[r] = acc0[r]; q0[r] = acc0[r] * acc0[r];
        s1[r] = acc1[r]; q1[r] = acc1[r] * acc1[r];
    }
#pragma unroll
    for (int off = 1; off < 16; off <<= 1) {
#pragma unroll
        for (int r = 0; r < 4; ++r) {
            s0[r] += __shfl_xor(s0[r], off); q0[r] += __shfl_xor(q0[r], off);
            s1[r] += __shfl_xor(s1[r], off); q1[r] += __shfl_xor(q1[r], off);
        }
    }
    if (lr == 0) {
#pragma unroll
        for (int r = 0; r < 4; ++r) {
            atomicAdd(&bs[lg * 4 + r], s0[r]);      atomicAdd(&bq[lg * 4 + r], q0[r]);
            atomicAdd(&bs[16 + lg * 4 + r], s1[r]); atomicAdd(&bq[16 + lg * 4 + r], q1[r]);
        }
    }
    __syncthreads();
    if (threadIdx.x < C_OUT) {
        atomicAdd(&sums[threadIdx.x], bs[threadIdx.x]);
        atomicAdd(&sums[C_OUT + threadIdx.x], bq[threadIdx.x]);
    }
}

// ---- BN + ReLU in-place ----
__global__ __launch_bounds__(256) void k_bnrelu(float* __restrict__ out,
                                                const float* __restrict__ sums,
                                                const float* __restrict__ gamma,
                                                const float* __restrict__ beta) {
    const size_t gid = (size_t)blockIdx.x * 256 + threadIdx.x;  // over float4s
    const int co = (int)(gid / (N_NODES / 4));
    const float inv_n = 1.0f / (float)N_NODES;
    const float mean = sums[co] * inv_n;
    const float var  = sums[C_OUT + co] * inv_n - mean * mean;
    const float scale = rsqrtf(var + BN_EPS) * gamma[co];
    const float bias  = beta[co] - mean * scale;

    float4* p = reinterpret_cast<float4*>(out);
    float4 v = p[gid];
    v.x = fmaxf(fmaf(v.x, scale, bias), 0.0f);
    v.y = fmaxf(fmaf(v.y, scale, bias), 0.0f);
    v.z = fmaxf(fmaf(v.z, scale, bias), 0.0f);
    v.w = fmaxf(fmaf(v.w, scale, bias), 0.0f);
    p[gid] = v;
}

extern "C" void kernel_launch(void* const* d_in, const int* in_sizes, int n_in,
                              void* d_out, int out_size, void* d_ws, size_t ws_size,
                              hipStream_t stream) {
    const float* data_in = (const float*)d_in[0];
    const int*   neigh   = (const int*)d_in[1];
    const float* weight  = (const float*)d_in[2];
    const float* gamma   = (const float*)d_in[3];
    const float* beta    = (const float*)d_in[4];
    float* out = (float*)d_out;

    unsigned short* xb   = (unsigned short*)d_ws;                 // N*32 bf16
    unsigned short* wlay = xb + (size_t)N_NODES * C_IN;           // 55296 B
    float* sums = (float*)(wlay + (size_t)KTAPS * 2 * 64 * 8);    // 64 f32

    k_prep<<<N_NODES / 256 + 1, 256, 0, stream>>>(data_in, weight, xb, wlay, sums);
    k_conv_mfma<<<N_NODES / 64, 256, 0, stream>>>(xb, neigh, wlay, out, sums);
    k_bnrelu<<<(N_NODES * C_OUT / 4) / 256, 256, 0, stream>>>(out, sums, gamma, beta);
}

// Round 12
// 89.402 us; speedup vs baseline: 3.5299x; 1.0105x over previous
//
#include <hip/hip_runtime.h>

#define N_NODES 131072
#define C_IN 32
#define C_OUT 32
#define KTAPS 27
#define BN_EPS 1e-5f

typedef __bf16 bf16x8 __attribute__((ext_vector_type(8)));
typedef float  f32x4  __attribute__((ext_vector_type(4)));

// ws layout:
//   xb   : N_NODES rows x 32 bf16 (node-major features)
//   wlay : 27 taps x 2 co-halves x 64 lanes x 8 bf16 (55296 B)
//   sums : 32 sum + 32 sumsq (f32)

static __device__ __forceinline__ unsigned short f2bf(float f) {
    unsigned int u = __float_as_uint(f);
    unsigned int r = (u + 0x7FFFu + ((u >> 16) & 1u)) >> 16;  // RNE
    return (unsigned short)r;
}

// ---- prep: blocks 0..511 transpose x; block 512 builds wlay + zeroes sums ----
__global__ __launch_bounds__(256) void k_prep(const float* __restrict__ in,
                                              const float* __restrict__ w,
                                              unsigned short* __restrict__ xb,
                                              unsigned short* __restrict__ wlay,
                                              float* __restrict__ sums) {
    if (blockIdx.x < N_NODES / 256) {
        const int n = blockIdx.x * 256 + threadIdx.x;
        unsigned short v[C_IN];
#pragma unroll
        for (int c = 0; c < C_IN; ++c) v[c] = f2bf(in[(size_t)c * N_NODES + n]);
        uint4* dst = reinterpret_cast<uint4*>(xb + (size_t)n * C_IN);
#pragma unroll
        for (int q = 0; q < 4; ++q) {
            uint4 pk;
            pk.x = (unsigned)v[q * 8 + 0] | ((unsigned)v[q * 8 + 1] << 16);
            pk.y = (unsigned)v[q * 8 + 2] | ((unsigned)v[q * 8 + 3] << 16);
            pk.z = (unsigned)v[q * 8 + 4] | ((unsigned)v[q * 8 + 5] << 16);
            pk.w = (unsigned)v[q * 8 + 6] | ((unsigned)v[q * 8 + 7] << 16);
            dst[q] = pk;
        }
    } else {
        if (threadIdx.x < 2 * C_OUT) sums[threadIdx.x] = 0.f;
        // A-frag (Out^T = W^T X^T, 16x16x32):
        // wlay[((k*2+h)*64+l)*8+j] = w[k*32 + (l>>4)*8+j][h*16 + (l&15)]
        for (int g = threadIdx.x; g < KTAPS * 2 * 64; g += 256) {
            const int k = g >> 7;
            const int rem = g & 127;
            const int h = rem >> 6;
            const int l = rem & 63;
            unsigned short wv[8];
#pragma unroll
            for (int j = 0; j < 8; ++j) {
                const int c  = ((l >> 4) << 3) + j;
                const int co = (h << 4) + (l & 15);
                wv[j] = f2bf(w[(size_t)(k * C_IN + c) * C_OUT + co]);
            }
            uint4 pk;
            pk.x = (unsigned)wv[0] | ((unsigned)wv[1] << 16);
            pk.y = (unsigned)wv[2] | ((unsigned)wv[3] << 16);
            pk.z = (unsigned)wv[4] | ((unsigned)wv[5] << 16);
            pk.w = (unsigned)wv[6] | ((unsigned)wv[7] << 16);
            *reinterpret_cast<uint4*>(wlay + (size_t)g * 8) = pk;
        }
    }
}

// ---- conv: EXACT round-2 core (16 nodes/wave, plain per-tap loop, compiler-
//      scheduled), plus post-loop fused BN-stats tail. ----
__global__ __launch_bounds__(256) void k_conv_mfma(const unsigned short* __restrict__ xb,
                                                   const int* __restrict__ neigh,
                                                   const unsigned short* __restrict__ wlay,
                                                   float* __restrict__ out,
                                                   float* __restrict__ sums) {
    __shared__ float bs[C_OUT];
    __shared__ float bq[C_OUT];
    if (threadIdx.x < C_OUT) { bs[threadIdx.x] = 0.f; bq[threadIdx.x] = 0.f; }

    const int wid  = threadIdx.x >> 6;
    const int lane = threadIdx.x & 63;
    const int lr   = lane & 15;   // node offset (B/D col)
    const int lg   = lane >> 4;   // channel-slice group
    const int nb   = blockIdx.x * 64 + wid * 16;

    // prefetch this lane's node's neighbor list
    const int* nrow = neigh + (size_t)(nb + lr) * KTAPS;
    int nidx[KTAPS];
#pragma unroll
    for (int k = 0; k < KTAPS; ++k) nidx[k] = nrow[k];

    f32x4 acc0 = {0.f, 0.f, 0.f, 0.f};
    f32x4 acc1 = {0.f, 0.f, 0.f, 0.f};

#pragma unroll
    for (int k = 0; k < KTAPS; ++k) {
        const bf16x8 xf = *reinterpret_cast<const bf16x8*>(xb + (size_t)nidx[k] * C_IN + lg * 8);
        const bf16x8 w0 = *reinterpret_cast<const bf16x8*>(wlay + ((size_t)(k * 2 + 0) * 64 + lane) * 8);
        const bf16x8 w1 = *reinterpret_cast<const bf16x8*>(wlay + ((size_t)(k * 2 + 1) * 64 + lane) * 8);
        acc0 = __builtin_amdgcn_mfma_f32_16x16x32_bf16(w0, xf, acc0, 0, 0, 0);
        acc1 = __builtin_amdgcn_mfma_f32_16x16x32_bf16(w1, xf, acc1, 0, 0, 0);
    }

    // D layout: col = lr -> node, row = lg*4 + r -> c_out
#pragma unroll
    for (int r = 0; r < 4; ++r) {
        out[(size_t)(lg * 4 + r) * N_NODES + nb + lr]      = acc0[r];
        out[(size_t)(16 + lg * 4 + r) * N_NODES + nb + lr] = acc1[r];
    }

    // fused BN stats tail: 16-lane in-register reduce -> LDS atomics -> global
    float s0[4], q0[4], s1[4], q1[4];
#pragma unroll
    for (int r = 0; r < 4; ++r) {
        s0[r] = acc0[r]; q0[r] = acc0[r] * acc0[r];
        s1[r] = acc1[r]; q1[r] = acc1[r] * acc1[r];
    }
#pragma unroll
    for (int off = 1; off < 16; off <<= 1) {
#pragma unroll
        for (int r = 0; r < 4; ++r) {
            s0[r] += __shfl_xor(s0[r], off); q0[r] += __shfl_xor(q0[r], off);
            s1[r] += __shfl_xor(s1[r], off); q1[r] += __shfl_xor(q1[r], off);
        }
    }
    __syncthreads();  // bs/bq init visible
    if (lr == 0) {
#pragma unroll
        for (int r = 0; r < 4; ++r) {
            atomicAdd(&bs[lg * 4 + r], s0[r]);      atomicAdd(&bq[lg * 4 + r], q0[r]);
            atomicAdd(&bs[16 + lg * 4 + r], s1[r]); atomicAdd(&bq[16 + lg * 4 + r], q1[r]);
        }
    }
    __syncthreads();
    if (threadIdx.x < C_OUT) {
        atomicAdd(&sums[threadIdx.x], bs[threadIdx.x]);
        atomicAdd(&sums[C_OUT + threadIdx.x], bq[threadIdx.x]);
    }
}

// ---- BN + ReLU in-place ----
__global__ __launch_bounds__(256) void k_bnrelu(float* __restrict__ out,
                                                const float* __restrict__ sums,
                                                const float* __restrict__ gamma,
                                                const float* __restrict__ beta) {
    const size_t gid = (size_t)blockIdx.x * 256 + threadIdx.x;  // over float4s
    const int co = (int)(gid / (N_NODES / 4));
    const float inv_n = 1.0f / (float)N_NODES;
    const float mean = sums[co] * inv_n;
    const float var  = sums[C_OUT + co] * inv_n - mean * mean;
    const float scale = rsqrtf(var + BN_EPS) * gamma[co];
    const float bias  = beta[co] - mean * scale;

    float4* p = reinterpret_cast<float4*>(out);
    float4 v = p[gid];
    v.x = fmaxf(fmaf(v.x, scale, bias), 0.0f);
    v.y = fmaxf(fmaf(v.y, scale, bias), 0.0f);
    v.z = fmaxf(fmaf(v.z, scale, bias), 0.0f);
    v.w = fmaxf(fmaf(v.w, scale, bias), 0.0f);
    p[gid] = v;
}

extern "C" void kernel_launch(void* const* d_in, const int* in_sizes, int n_in,
                              void* d_out, int out_size, void* d_ws, size_t ws_size,
                              hipStream_t stream) {
    const float* data_in = (const float*)d_in[0];
    const int*   neigh   = (const int*)d_in[1];
    const float* weight  = (const float*)d_in[2];
    const float* gamma   = (const float*)d_in[3];
    const float* beta    = (const float*)d_in[4];
    float* out = (float*)d_out;

    unsigned short* xb   = (unsigned short*)d_ws;                 // N*32 bf16
    unsigned short* wlay = xb + (size_t)N_NODES * C_IN;           // 55296 B
    float* sums = (float*)(wlay + (size_t)KTAPS * 2 * 64 * 8);    // 64 f32

    k_prep<<<N_NODES / 256 + 1, 256, 0, stream>>>(data_in, weight, xb, wlay, sums);
    k_conv_mfma<<<N_NODES / 64, 256, 0, stream>>>(xb, neigh, wlay, out, sums);
    k_bnrelu<<<(N_NODES * C_OUT / 4) / 256, 256, 0, stream>>>(out, sums, gamma, beta);
}

// Round 13
// 79.444 us; speedup vs baseline: 3.9724x; 1.1253x over previous
//
#include <hip/hip_runtime.h>

#define N_NODES 131072
#define C_IN 32
#define C_OUT 32
#define KTAPS 27
#define BN_EPS 1e-5f

typedef __bf16 bf16x8 __attribute__((ext_vector_type(8)));
typedef float  f32x4  __attribute__((ext_vector_type(4)));

// ws layout:
//   xb   : N_NODES rows x 32 bf16 (node-major features)
//   wlay : 27 taps x 2 co-halves x 64 lanes x 8 bf16 (55296 B)
//   sums : 32 sum + 32 sumsq (f32)

static __device__ __forceinline__ unsigned short f2bf(float f) {
    unsigned int u = __float_as_uint(f);
    unsigned int r = (u + 0x7FFFu + ((u >> 16) & 1u)) >> 16;  // RNE
    return (unsigned short)r;
}

// ---- prep: blocks 0..511 transpose x; block 512 builds wlay + zeroes sums ----
__global__ __launch_bounds__(256) void k_prep(const float* __restrict__ in,
                                              const float* __restrict__ w,
                                              unsigned short* __restrict__ xb,
                                              unsigned short* __restrict__ wlay,
                                              float* __restrict__ sums) {
    if (blockIdx.x < N_NODES / 256) {
        const int n = blockIdx.x * 256 + threadIdx.x;
        unsigned short v[C_IN];
#pragma unroll
        for (int c = 0; c < C_IN; ++c) v[c] = f2bf(in[(size_t)c * N_NODES + n]);
        uint4* dst = reinterpret_cast<uint4*>(xb + (size_t)n * C_IN);
#pragma unroll
        for (int q = 0; q < 4; ++q) {
            uint4 pk;
            pk.x = (unsigned)v[q * 8 + 0] | ((unsigned)v[q * 8 + 1] << 16);
            pk.y = (unsigned)v[q * 8 + 2] | ((unsigned)v[q * 8 + 3] << 16);
            pk.z = (unsigned)v[q * 8 + 4] | ((unsigned)v[q * 8 + 5] << 16);
            pk.w = (unsigned)v[q * 8 + 6] | ((unsigned)v[q * 8 + 7] << 16);
            dst[q] = pk;
        }
    } else {
        if (threadIdx.x < 2 * C_OUT) sums[threadIdx.x] = 0.f;
        // A-frag (Out^T = W^T X^T, 16x16x32):
        // wlay[((k*2+h)*64+l)*8+j] = w[k*32 + (l>>4)*8+j][h*16 + (l&15)]
        for (int g = threadIdx.x; g < KTAPS * 2 * 64; g += 256) {
            const int k = g >> 7;
            const int rem = g & 127;
            const int h = rem >> 6;
            const int l = rem & 63;
            unsigned short wv[8];
#pragma unroll
            for (int j = 0; j < 8; ++j) {
                const int c  = ((l >> 4) << 3) + j;
                const int co = (h << 4) + (l & 15);
                wv[j] = f2bf(w[(size_t)(k * C_IN + c) * C_OUT + co]);
            }
            uint4 pk;
            pk.x = (unsigned)wv[0] | ((unsigned)wv[1] << 16);
            pk.y = (unsigned)wv[2] | ((unsigned)wv[3] << 16);
            pk.z = (unsigned)wv[4] | ((unsigned)wv[5] << 16);
            pk.w = (unsigned)wv[6] | ((unsigned)wv[7] << 16);
            *reinterpret_cast<uint4*>(wlay + (size_t)g * 8) = pk;
        }
    }
}

// ---- conv: EXACT round-2 kernel — no LDS, no barriers, no stats tail ----
__global__ __launch_bounds__(256) void k_conv_mfma(const unsigned short* __restrict__ xb,
                                                   const int* __restrict__ neigh,
                                                   const unsigned short* __restrict__ wlay,
                                                   float* __restrict__ out) {
    const int wid  = threadIdx.x >> 6;
    const int lane = threadIdx.x & 63;
    const int lr   = lane & 15;   // node offset (B/D col)
    const int lg   = lane >> 4;   // channel-slice group
    const int nb   = blockIdx.x * 64 + wid * 16;

    // prefetch this lane's node's neighbor list
    const int* nrow = neigh + (size_t)(nb + lr) * KTAPS;
    int nidx[KTAPS];
#pragma unroll
    for (int k = 0; k < KTAPS; ++k) nidx[k] = nrow[k];

    f32x4 acc0 = {0.f, 0.f, 0.f, 0.f};
    f32x4 acc1 = {0.f, 0.f, 0.f, 0.f};

#pragma unroll
    for (int k = 0; k < KTAPS; ++k) {
        const bf16x8 xf = *reinterpret_cast<const bf16x8*>(xb + (size_t)nidx[k] * C_IN + lg * 8);
        const bf16x8 w0 = *reinterpret_cast<const bf16x8*>(wlay + ((size_t)(k * 2 + 0) * 64 + lane) * 8);
        const bf16x8 w1 = *reinterpret_cast<const bf16x8*>(wlay + ((size_t)(k * 2 + 1) * 64 + lane) * 8);
        acc0 = __builtin_amdgcn_mfma_f32_16x16x32_bf16(w0, xf, acc0, 0, 0, 0);
        acc1 = __builtin_amdgcn_mfma_f32_16x16x32_bf16(w1, xf, acc1, 0, 0, 0);
    }

    // D layout: col = lr -> node, row = lg*4 + r -> c_out
#pragma unroll
    for (int r = 0; r < 4; ++r) {
        out[(size_t)(lg * 4 + r) * N_NODES + nb + lr]      = acc0[r];
        out[(size_t)(16 + lg * 4 + r) * N_NODES + nb + lr] = acc1[r];
    }
}

// ---- BN stats over pre-BN out (channel-major, coalesced; 512 atomics total) ----
__global__ __launch_bounds__(256) void k_stats(const float* __restrict__ out,
                                               float* __restrict__ sums) {
    const int c     = blockIdx.x >> 3;
    const int chunk = blockIdx.x & 7;
    const float4* base = reinterpret_cast<const float4*>(out + (size_t)c * N_NODES + chunk * (N_NODES / 8));
    float s = 0.f, s2 = 0.f;
    for (int i = threadIdx.x; i < N_NODES / 8 / 4; i += 256) {
        float4 v = base[i];
        s  += v.x + v.y + v.z + v.w;
        s2 += v.x * v.x + v.y * v.y + v.z * v.z + v.w * v.w;
    }
#pragma unroll
    for (int off = 32; off >= 1; off >>= 1) {
        s  += __shfl_xor(s,  off);
        s2 += __shfl_xor(s2, off);
    }
    __shared__ float ls[8];
    const int wid = threadIdx.x >> 6;
    if ((threadIdx.x & 63) == 0) { ls[wid * 2] = s; ls[wid * 2 + 1] = s2; }
    __syncthreads();
    if (threadIdx.x == 0) {
        float ts  = ls[0] + ls[2] + ls[4] + ls[6];
        float ts2 = ls[1] + ls[3] + ls[5] + ls[7];
        atomicAdd(&sums[c], ts);
        atomicAdd(&sums[C_OUT + c], ts2);
    }
}

// ---- BN + ReLU in-place ----
__global__ __launch_bounds__(256) void k_bnrelu(float* __restrict__ out,
                                                const float* __restrict__ sums,
                                                const float* __restrict__ gamma,
                                                const float* __restrict__ beta) {
    const size_t gid = (size_t)blockIdx.x * 256 + threadIdx.x;  // over float4s
    const int co = (int)(gid / (N_NODES / 4));
    const float inv_n = 1.0f / (float)N_NODES;
    const float mean = sums[co] * inv_n;
    const float var  = sums[C_OUT + co] * inv_n - mean * mean;
    const float scale = rsqrtf(var + BN_EPS) * gamma[co];
    const float bias  = beta[co] - mean * scale;

    float4* p = reinterpret_cast<float4*>(out);
    float4 v = p[gid];
    v.x = fmaxf(fmaf(v.x, scale, bias), 0.0f);
    v.y = fmaxf(fmaf(v.y, scale, bias), 0.0f);
    v.z = fmaxf(fmaf(v.z, scale, bias), 0.0f);
    v.w = fmaxf(fmaf(v.w, scale, bias), 0.0f);
    p[gid] = v;
}

extern "C" void kernel_launch(void* const* d_in, const int* in_sizes, int n_in,
                              void* d_out, int out_size, void* d_ws, size_t ws_size,
                              hipStream_t stream) {
    const float* data_in = (const float*)d_in[0];
    const int*   neigh   = (const int*)d_in[1];
    const float* weight  = (const float*)d_in[2];
    const float* gamma   = (const float*)d_in[3];
    const float* beta    = (const float*)d_in[4];
    float* out = (float*)d_out;

    unsigned short* xb   = (unsigned short*)d_ws;                 // N*32 bf16
    unsigned short* wlay = xb + (size_t)N_NODES * C_IN;           // 55296 B
    float* sums = (float*)(wlay + (size_t)KTAPS * 2 * 64 * 8);    // 64 f32

    k_prep<<<N_NODES / 256 + 1, 256, 0, stream>>>(data_in, weight, xb, wlay, sums);
    k_conv_mfma<<<N_NODES / 64, 256, 0, stream>>>(xb, neigh, wlay, out);
    k_stats<<<C_OUT * 8, 256, 0, stream>>>(out, sums);
    k_bnrelu<<<(N_NODES * C_OUT / 4) / 256, 256, 0, stream>>>(out, sums, gamma, beta);
}

// Round 14
// 73.366 us; speedup vs baseline: 4.3015x; 1.0828x over previous
//
#include <hip/hip_runtime.h>

#define N_NODES 131072
#define C_IN 32
#define C_OUT 32
#define KTAPS 27
#define BN_EPS 1e-5f

typedef __bf16 bf16x8 __attribute__((ext_vector_type(8)));
typedef float  f32x4  __attribute__((ext_vector_type(4)));

// ws layout:
//   xb   : N_NODES rows x 32 bf16 (node-major features)
//   wlay : 27 taps x 2 co-halves x 64 lanes x 8 bf16 (55296 B)
//   sums : 32 sum + 32 sumsq (f32)

static __device__ __forceinline__ unsigned short f2bf(float f) {
    unsigned int u = __float_as_uint(f);
    unsigned int r = (u + 0x7FFFu + ((u >> 16) & 1u)) >> 16;  // RNE
    return (unsigned short)r;
}

// ---- prep: blocks 0..511 transpose x; block 512 builds wlay + zeroes sums ----
__global__ __launch_bounds__(256) void k_prep(const float* __restrict__ in,
                                              const float* __restrict__ w,
                                              unsigned short* __restrict__ xb,
                                              unsigned short* __restrict__ wlay,
                                              float* __restrict__ sums) {
    if (blockIdx.x < N_NODES / 256) {
        const int n = blockIdx.x * 256 + threadIdx.x;
        unsigned short v[C_IN];
#pragma unroll
        for (int c = 0; c < C_IN; ++c) v[c] = f2bf(in[(size_t)c * N_NODES + n]);
        uint4* dst = reinterpret_cast<uint4*>(xb + (size_t)n * C_IN);
#pragma unroll
        for (int q = 0; q < 4; ++q) {
            uint4 pk;
            pk.x = (unsigned)v[q * 8 + 0] | ((unsigned)v[q * 8 + 1] << 16);
            pk.y = (unsigned)v[q * 8 + 2] | ((unsigned)v[q * 8 + 3] << 16);
            pk.z = (unsigned)v[q * 8 + 4] | ((unsigned)v[q * 8 + 5] << 16);
            pk.w = (unsigned)v[q * 8 + 6] | ((unsigned)v[q * 8 + 7] << 16);
            dst[q] = pk;
        }
    } else {
        if (threadIdx.x < 2 * C_OUT) sums[threadIdx.x] = 0.f;
        // A-frag (Out^T = W^T X^T, 16x16x32):
        // wlay[((k*2+h)*64+l)*8+j] = w[k*32 + (l>>4)*8+j][h*16 + (l&15)]
        for (int g = threadIdx.x; g < KTAPS * 2 * 64; g += 256) {
            const int k = g >> 7;
            const int rem = g & 127;
            const int h = rem >> 6;
            const int l = rem & 63;
            unsigned short wv[8];
#pragma unroll
            for (int j = 0; j < 8; ++j) {
                const int c  = ((l >> 4) << 3) + j;
                const int co = (h << 4) + (l & 15);
                wv[j] = f2bf(w[(size_t)(k * C_IN + c) * C_OUT + co]);
            }
            uint4 pk;
            pk.x = (unsigned)wv[0] | ((unsigned)wv[1] << 16);
            pk.y = (unsigned)wv[2] | ((unsigned)wv[3] << 16);
            pk.z = (unsigned)wv[4] | ((unsigned)wv[5] << 16);
            pk.w = (unsigned)wv[6] | ((unsigned)wv[7] << 16);
            *reinterpret_cast<uint4*>(wlay + (size_t)g * 8) = pk;
        }
    }
}

// ---- conv: SINGLE pass, weights in LDS, 512 co-resident 1024-thr blocks,
//      16 nodes/wave, fused BN stats (r7 shell minus the pass machinery).
//      Per wave: 27 gather instrs total — 3x fewer L1 line-requests than any
//      prior config (r2 spent them on weights, r7 on 3x gathers). ----
__global__ __launch_bounds__(1024) void k_conv_mfma(const unsigned short* __restrict__ xb,
                                                    const int* __restrict__ neigh,
                                                    const unsigned short* __restrict__ wlay,
                                                    float* __restrict__ out,
                                                    float* __restrict__ sums) {
    __shared__ unsigned short wl[KTAPS * 2 * 64 * 8];  // 55296 B
    __shared__ float bs[C_OUT];
    __shared__ float bq[C_OUT];

    {   // stage weight table (3456 uint4 over 1024 threads)
        const uint4* src = reinterpret_cast<const uint4*>(wlay);
        uint4* d = reinterpret_cast<uint4*>(wl);
        for (int i = threadIdx.x; i < KTAPS * 2 * 64; i += 1024) d[i] = src[i];
    }
    if (threadIdx.x < C_OUT) { bs[threadIdx.x] = 0.f; bq[threadIdx.x] = 0.f; }
    __syncthreads();

    const int wid  = threadIdx.x >> 6;   // 0..15
    const int lane = threadIdx.x & 63;
    const int lr   = lane & 15;          // node offset (B/D col)
    const int lg   = lane >> 4;          // channel-slice group
    const int nb   = blockIdx.x * 256 + wid * 16;

    // neighbor list for this lane's node, held in VGPRs
    const int* nrow = neigh + (size_t)(nb + lr) * KTAPS;
    int nidx[KTAPS];
#pragma unroll
    for (int k = 0; k < KTAPS; ++k) nidx[k] = nrow[k];

    f32x4 acc0 = {0.f, 0.f, 0.f, 0.f};
    f32x4 acc1 = {0.f, 0.f, 0.f, 0.f};

#pragma unroll
    for (int k = 0; k < KTAPS; ++k) {
        const bf16x8 xf = *reinterpret_cast<const bf16x8*>(xb + (size_t)nidx[k] * C_IN + lg * 8);
        const bf16x8 w0 = *reinterpret_cast<const bf16x8*>(wl + ((size_t)(k * 2 + 0) * 64 + lane) * 8);
        const bf16x8 w1 = *reinterpret_cast<const bf16x8*>(wl + ((size_t)(k * 2 + 1) * 64 + lane) * 8);
        acc0 = __builtin_amdgcn_mfma_f32_16x16x32_bf16(w0, xf, acc0, 0, 0, 0);
        acc1 = __builtin_amdgcn_mfma_f32_16x16x32_bf16(w1, xf, acc1, 0, 0, 0);
    }

    // D layout: col = lr -> node, row = lg*4 + r -> c_out
#pragma unroll
    for (int r = 0; r < 4; ++r) {
        out[(size_t)(lg * 4 + r) * N_NODES + nb + lr]      = acc0[r];
        out[(size_t)(16 + lg * 4 + r) * N_NODES + nb + lr] = acc1[r];
    }

    // fused BN stats: 16-lane in-register reduce -> LDS atomics -> global
    // (512-block atomic depth: measured OK inside r7's 57 µs kernel)
    float s0[4], q0[4], s1[4], q1[4];
#pragma unroll
    for (int r = 0; r < 4; ++r) {
        s0[r] = acc0[r]; q0[r] = acc0[r] * acc0[r];
        s1[r] = acc1[r]; q1[r] = acc1[r] * acc1[r];
    }
#pragma unroll
    for (int off = 1; off < 16; off <<= 1) {
#pragma unroll
        for (int r = 0; r < 4; ++r) {
            s0[r] += __shfl_xor(s0[r], off); q0[r] += __shfl_xor(q0[r], off);
            s1[r] += __shfl_xor(s1[r], off); q1[r] += __shfl_xor(q1[r], off);
        }
    }
    if (lr == 0) {
#pragma unroll
        for (int r = 0; r < 4; ++r) {
            atomicAdd(&bs[lg * 4 + r], s0[r]);      atomicAdd(&bq[lg * 4 + r], q0[r]);
            atomicAdd(&bs[16 + lg * 4 + r], s1[r]); atomicAdd(&bq[16 + lg * 4 + r], q1[r]);
        }
    }
    __syncthreads();
    if (threadIdx.x < C_OUT) {
        atomicAdd(&sums[threadIdx.x], bs[threadIdx.x]);
        atomicAdd(&sums[C_OUT + threadIdx.x], bq[threadIdx.x]);
    }
}

// ---- BN + ReLU in-place ----
__global__ __launch_bounds__(256) void k_bnrelu(float* __restrict__ out,
                                                const float* __restrict__ sums,
                                                const float* __restrict__ gamma,
                                                const float* __restrict__ beta) {
    const size_t gid = (size_t)blockIdx.x * 256 + threadIdx.x;  // over float4s
    const int co = (int)(gid / (N_NODES / 4));
    const float inv_n = 1.0f / (float)N_NODES;
    const float mean = sums[co] * inv_n;
    const float var  = sums[C_OUT + co] * inv_n - mean * mean;
    const float scale = rsqrtf(var + BN_EPS) * gamma[co];
    const float bias  = beta[co] - mean * scale;

    float4* p = reinterpret_cast<float4*>(out);
    float4 v = p[gid];
    v.x = fmaxf(fmaf(v.x, scale, bias), 0.0f);
    v.y = fmaxf(fmaf(v.y, scale, bias), 0.0f);
    v.z = fmaxf(fmaf(v.z, scale, bias), 0.0f);
    v.w = fmaxf(fmaf(v.w, scale, bias), 0.0f);
    p[gid] = v;
}

extern "C" void kernel_launch(void* const* d_in, const int* in_sizes, int n_in,
                              void* d_out, int out_size, void* d_ws, size_t ws_size,
                              hipStream_t stream) {
    const float* data_in = (const float*)d_in[0];
    const int*   neigh   = (const int*)d_in[1];
    const float* weight  = (const float*)d_in[2];
    const float* gamma   = (const float*)d_in[3];
    const float* beta    = (const float*)d_in[4];
    float* out = (float*)d_out;

    unsigned short* xb   = (unsigned short*)d_ws;                 // N*32 bf16
    unsigned short* wlay = xb + (size_t)N_NODES * C_IN;           // 55296 B
    float* sums = (float*)(wlay + (size_t)KTAPS * 2 * 64 * 8);    // 64 f32

    k_prep<<<N_NODES / 256 + 1, 256, 0, stream>>>(data_in, weight, xb, wlay, sums);
    k_conv_mfma<<<N_NODES / 256, 1024, 0, stream>>>(xb, neigh, wlay, out, sums);
    k_bnrelu<<<(N_NODES * C_OUT / 4) / 256, 256, 0, stream>>>(out, sums, gamma, beta);
}